// Round 8
// baseline (322.151 us; speedup 1.0000x reference)
//
#include <hip/hip_runtime.h>

// TV denoiser (Chambolle-Pock), 40 iterations = 5 launches x 8 fused steps.
// Temporal blocking on an 80x80 staged region -> central 64x64 output.
//
// Round-8 structure: LDS-issue was the bottleneck (12 b32 LDS ops/cell/step
// ~= measured 47 us/dispatch). Now each thread owns a PAIR of adjacent
// columns x 5 row-passes; own-cell u0/u1/x2/y/w live in REGISTERS, LDS only
// carries cross-thread values: phase1 reads su0[l-S] (b64) + su1[l-1] (b32),
// writes sw (b64); phase2 reads sw[l+S] (b64) + sw[l+2] (b32), writes
// su0/su1 (b64) -> 3.5 LDS ops/cell/step (3.4x fewer).
//
// Phase 1 is UNCONDITIONAL (w garbage outside the valid cone is provably
// never read by an active phase-2 cell). Phase 2 uses per-cell ?: selects
// (NaN-safe) and always writes u back (inactive cells rewrite old value);
// OOB-of-image cells therefore stay exactly 0 (round-2 invariant).
// Base-shifted LDS + zeroed pads keep every neighbor read in-bounds.
//
// first=1: u==0, x2==y (skips loads; replaces the 41us memset).
// last=1: skip u stores (u_39 is dead).

#define Hh 512
#define Ww 512
#define Bb 8
#define TS 64
#define KF 8
#define S  80
#define SS (S*S)       // 6400
#define NT 640
#define NKP 5          // row passes; 16 rows per pass, 2 cols per thread

__global__ __launch_bounds__(NT, 5)
void tv_fused(const float*  __restrict__ x2_in,
              const float4* __restrict__ u_in,
              const float*  __restrict__ y_in,
              float*  __restrict__ x2_out,
              float4* __restrict__ u_out,
              int first, int last)
{
    constexpr float TAU = 0.01f;
    constexpr float RHO = 1.99f;
    constexpr float SIGMA = 12.5f;       // 1/TAU/8
    constexpr float THS = 0.1f;
    constexpr float INV_1PT = 1.0f / 1.01f;

    __shared__ float su0_raw[SS + S];      // su0p = raw + S  (row -1 -> zeroed pad)
    __shared__ float su1_raw[SS + 4];      // su1p = raw + 2  (col -1 -> zeroed pad)
    __shared__ float sw_raw [SS + S + 4];  // reads up to l+S+1 -> zeroed pad

    float* su0p = su0_raw + S;
    float* su1p = su1_raw + 2;

    const int b   = blockIdx.z;
    const int r0  = blockIdx.y * TS;
    const int c0  = blockIdx.x * TS;
    const int tid = threadIdx.x;
    const size_t plane = (size_t)b * (Hh * Ww);

    const int rp = tid / 40;            // 0..15
    const int cp = tid - rp * 40;       // 0..39
    const int lc = 2 * cp;
    const int gc = c0 - KF + lc;        // even; image col of left cell
    const bool colin = (gc >= 0) & (gc < Ww);
    const float ewL = (gc     < Ww - 1) ? 1.f : 0.f;
    const float ewR = (gc + 1 < Ww - 1) ? 1.f : 0.f;
    const int l0 = rp * S + lc;

    float u0L[NKP], u0R[NKP], u1L[NKP], u1R[NKP];
    float x2L[NKP], x2R[NKP], yL[NKP], yR[NKP], wL[NKP], wR[NKP];
    float ehf[NKP];
    int   tm2L[NKP], tm2R[NKP];

    // zero the pads (read-only regions)
    if (tid < S)     su0_raw[tid] = 0.f;
    if (tid < 2)     su1_raw[tid] = 0.f;
    if (tid < S + 4) sw_raw[SS + tid] = 0.f;

    // ---- stage
    #pragma unroll
    for (int k = 0; k < NKP; ++k) {
        const int lr = rp + 16 * k;
        const int gr = r0 - KF + lr;
        const int l  = l0 + 1280 * k;
        const bool img = colin & (gr >= 0) & (gr < Hh);
        float a0 = 0.f, a1 = 0.f, u0l = 0.f, u1l = 0.f, u0r = 0.f, u1r = 0.f;
        float yl = 0.f, yrr = 0.f;
        if (img) {
            size_t gi = plane + (size_t)gr * Ww + gc;
            float2 yv = *(const float2*)&y_in[gi];
            yl = yv.x; yrr = yv.y;
            if (first) { a0 = yl; a1 = yrr; }
            else {
                float2 xv = *(const float2*)&x2_in[gi];
                a0 = xv.x; a1 = xv.y;
                float4 uv = u_in[gi >> 1];
                u0l = uv.x; u1l = uv.y; u0r = uv.z; u1r = uv.w;
            }
        }
        u0L[k] = u0l; u1L[k] = u1l; u0R[k] = u0r; u1R[k] = u1r;
        x2L[k] = a0;  x2R[k] = a1;  yL[k] = yl;   yR[k] = yrr;
        ehf[k] = (gr < Hh - 1) ? 1.f : 0.f;
        int mL = min(min(lr, S - 1 - lr), min(lc,     S - 1 - lc));
        int mR = min(min(lr, S - 1 - lr), min(lc + 1, S - 2 - lc));
        tm2L[k] = img ? mL : 0;
        tm2R[k] = img ? mR : 0;
        *(float2*)&su0p[l] = make_float2(u0l, u0r);
        *(float2*)&su1p[l] = make_float2(u1l, u1r);
    }
    __syncthreads();

    for (int t = 0; t < KF; ++t) {
        // ---- phase 1 (unconditional): w = 2x - x2
        #pragma unroll
        for (int k = 0; k < NKP; ++k) {
            const int l = l0 + 1280 * k;
            float2 ua = *(const float2*)&su0p[l - S];   // u0 above (b64)
            float  uw = su1p[l - 1];                    // u1 left-of-left (b32)
            float adjL = ua.x - u0L[k] + uw     - u1L[k];
            float adjR = ua.y - u0R[k] + u1L[k] - u1R[k];
            float xL = fmaf(TAU, yL[k] - adjL, x2L[k]);     // x*(1+TAU)
            float xR = fmaf(TAU, yR[k] - adjR, x2R[k]);
            wL[k] = fmaf(2.0f * INV_1PT, xL, -x2L[k]);      // 2x - x2
            wR[k] = fmaf(2.0f * INV_1PT, xR, -x2R[k]);
            *(float2*)&sw_raw[l] = make_float2(wL[k], wR[k]);
        }
        __syncthreads();
        // ---- phase 2: u, x2 update (selects keep inactive/OOB cells frozen)
        #pragma unroll
        for (int k = 0; k < NKP; ++k) {
            const int l = l0 + 1280 * k;
            float2 wb = *(const float2*)&sw_raw[l + S]; // w below (b64)
            float  wr = sw_raw[l + 2];                  // w right-of-right (b32)
            float dhL = ehf[k] * (wb.x - wL[k]);
            float dhR = ehf[k] * (wb.y - wR[k]);
            float dwL = ewL * (wR[k] - wL[k]);
            float dwR = ewR * (wr    - wR[k]);
            float v0L = fmaf(SIGMA, dhL, u0L[k]);
            float v1L = fmaf(SIGMA, dwL, u1L[k]);
            float v0R = fmaf(SIGMA, dhR, u0R[k]);
            float v1R = fmaf(SIGMA, dwR, u1R[k]);
            float ivL = fminf(THS * __builtin_amdgcn_rsqf(fmaf(v0L, v0L, v1L * v1L)), 1.f);
            float ivR = fminf(THS * __builtin_amdgcn_rsqf(fmaf(v0R, v0R, v1R * v1R)), 1.f);
            bool aL = t < tm2L[k], aR = t < tm2R[k];
            u0L[k] = aL ? fmaf(RHO, v0L * ivL - u0L[k], u0L[k]) : u0L[k];
            u1L[k] = aL ? fmaf(RHO, v1L * ivL - u1L[k], u1L[k]) : u1L[k];
            x2L[k] = aL ? fmaf(0.5f * RHO, wL[k] - x2L[k], x2L[k]) : x2L[k];
            u0R[k] = aR ? fmaf(RHO, v0R * ivR - u0R[k], u0R[k]) : u0R[k];
            u1R[k] = aR ? fmaf(RHO, v1R * ivR - u1R[k], u1R[k]) : u1R[k];
            x2R[k] = aR ? fmaf(0.5f * RHO, wR[k] - x2R[k], x2R[k]) : x2R[k];
            *(float2*)&su0p[l] = make_float2(u0L[k], u0R[k]);
            *(float2*)&su1p[l] = make_float2(u1L[k], u1R[k]);
        }
        __syncthreads();
    }

    // ---- store central 64x64 straight from registers
    if (cp >= 4 && cp < 36) {
        #pragma unroll
        for (int k = 0; k < NKP; ++k) {
            const int lr = rp + 16 * k;
            if (lr >= KF && lr < KF + TS) {
                size_t gi = plane + (size_t)(r0 + lr - KF) * Ww + gc;
                *(float2*)&x2_out[gi] = make_float2(x2L[k], x2R[k]);
                if (!last) u_out[gi >> 1] = make_float4(u0L[k], u1L[k], u0R[k], u1R[k]);
            }
        }
    }
}

extern "C" void kernel_launch(void* const* d_in, const int* in_sizes, int n_in,
                              void* d_out, int out_size, void* d_ws, size_t ws_size,
                              hipStream_t stream)
{
    const float* y = (const float*)d_in[0];
    float* out = (float*)d_out;
    const size_t NP = (size_t)Bb * Hh * Ww;   // 2M cells

    float*  ws  = (float*)d_ws;
    float*  x2A = ws;                          // 8 MB
    float*  x2B = ws + NP;                     // 8 MB
    float4* uA  = (float4*)(ws + 2 * NP);      // 16 MB
    float4* uB  = (float4*)(ws + 4 * NP);      // 16 MB
    // total ws use: 6*NP*4 = 48 MB; no memset needed (first=1 treats u as 0)

    dim3 grid(Ww / TS, Hh / TS, Bb);   // 8 x 8 x 8 = 512 blocks

    tv_fused<<<grid, NT, 0, stream>>>(y,   uB, y, x2A, uA, 1, 0);
    tv_fused<<<grid, NT, 0, stream>>>(x2A, uA, y, x2B, uB, 0, 0);
    tv_fused<<<grid, NT, 0, stream>>>(x2B, uB, y, x2A, uA, 0, 0);
    tv_fused<<<grid, NT, 0, stream>>>(x2A, uA, y, x2B, uB, 0, 0);
    tv_fused<<<grid, NT, 0, stream>>>(x2B, uB, y, out, uA, 0, 1);
}

// Round 9
// 244.118 us; speedup vs baseline: 1.3197x; 1.3197x over previous
//
#include <hip/hip_runtime.h>

// TV denoiser (Chambolle-Pock), 40 iterations = 5 launches x 8 fused steps.
// Temporal blocking on an 80x80 staged region -> central 64x64 output.
//
// Round-9 fix: __launch_bounds__(640, 5) was interpreted with CUDA
// blocks-per-SM-like semantics (observed VGPR_Count=48 ~= 512/12.5), forcing
// ~30 spilled slots/thread -> scratch traffic (WRITE 24.5->55.6 MB) and the
// round-8 regression. (640, 2) allows >=102 VGPRs under either semantics;
// LDS (77 KB) already caps residency at 2 blocks/CU so nothing is lost.
//
// Structure (round 8): each thread owns a PAIR of adjacent columns x 5 row
// passes; own-cell u0/u1/x2/y/w in REGISTERS, LDS only for cross-thread
// exchange: phase1 reads su0[l-S] (b64) + su1[l-1] (b32), writes sw (b64);
// phase2 reads sw[l+S] (b64) + sw[l+2] (b32), writes su0/su1 (b64)
// -> 3.5 LDS ops/cell/step (vs 12 in round 7).
//
// Phase 1 is unconditional (w garbage outside the valid cone is provably
// never read by an active phase-2 cell). Phase 2 uses ?: selects and always
// writes u back; OOB-of-image cells stay exactly 0 (round-2 invariant).
// Base-shifted LDS + zeroed pads keep every neighbor read in-bounds.
//
// first=1: u==0, x2==y (skips loads; replaces the 41us memset).
// last=1: skip u stores (u_39 is dead).

#define Hh 512
#define Ww 512
#define Bb 8
#define TS 64
#define KF 8
#define S  80
#define SS (S*S)       // 6400
#define NT 640
#define NKP 5          // row passes; 16 rows per pass, 2 cols per thread

__global__ __launch_bounds__(NT, 2)
void tv_fused(const float*  __restrict__ x2_in,
              const float4* __restrict__ u_in,
              const float*  __restrict__ y_in,
              float*  __restrict__ x2_out,
              float4* __restrict__ u_out,
              int first, int last)
{
    constexpr float TAU = 0.01f;
    constexpr float RHO = 1.99f;
    constexpr float SIGMA = 12.5f;       // 1/TAU/8
    constexpr float THS = 0.1f;
    constexpr float INV_1PT = 1.0f / 1.01f;

    __shared__ float su0_raw[SS + S];      // su0p = raw + S  (row -1 -> zeroed pad)
    __shared__ float su1_raw[SS + 4];      // su1p = raw + 2  (col -1 -> zeroed pad)
    __shared__ float sw_raw [SS + S + 4];  // reads up to l+S+1 -> zeroed pad

    float* su0p = su0_raw + S;
    float* su1p = su1_raw + 2;

    const int b   = blockIdx.z;
    const int r0  = blockIdx.y * TS;
    const int c0  = blockIdx.x * TS;
    const int tid = threadIdx.x;
    const size_t plane = (size_t)b * (Hh * Ww);

    const int rp = tid / 40;            // 0..15
    const int cp = tid - rp * 40;       // 0..39
    const int lc = 2 * cp;
    const int gc = c0 - KF + lc;        // even; image col of left cell
    const bool colin = (gc >= 0) & (gc < Ww);
    const float ewL = (gc     < Ww - 1) ? 1.f : 0.f;
    const float ewR = (gc + 1 < Ww - 1) ? 1.f : 0.f;
    const int l0 = rp * S + lc;

    float u0L[NKP], u0R[NKP], u1L[NKP], u1R[NKP];
    float x2L[NKP], x2R[NKP], yL[NKP], yR[NKP], wL[NKP], wR[NKP];
    float ehf[NKP];
    int   tm2L[NKP], tm2R[NKP];

    // zero the pads (read-only regions)
    if (tid < S)     su0_raw[tid] = 0.f;
    if (tid < 2)     su1_raw[tid] = 0.f;
    if (tid < S + 4) sw_raw[SS + tid] = 0.f;

    // ---- stage
    #pragma unroll
    for (int k = 0; k < NKP; ++k) {
        const int lr = rp + 16 * k;
        const int gr = r0 - KF + lr;
        const int l  = l0 + 1280 * k;
        const bool img = colin & (gr >= 0) & (gr < Hh);
        float a0 = 0.f, a1 = 0.f, u0l = 0.f, u1l = 0.f, u0r = 0.f, u1r = 0.f;
        float yl = 0.f, yrr = 0.f;
        if (img) {
            size_t gi = plane + (size_t)gr * Ww + gc;
            float2 yv = *(const float2*)&y_in[gi];
            yl = yv.x; yrr = yv.y;
            if (first) { a0 = yl; a1 = yrr; }
            else {
                float2 xv = *(const float2*)&x2_in[gi];
                a0 = xv.x; a1 = xv.y;
                float4 uv = u_in[gi >> 1];
                u0l = uv.x; u1l = uv.y; u0r = uv.z; u1r = uv.w;
            }
        }
        u0L[k] = u0l; u1L[k] = u1l; u0R[k] = u0r; u1R[k] = u1r;
        x2L[k] = a0;  x2R[k] = a1;  yL[k] = yl;   yR[k] = yrr;
        ehf[k] = (gr < Hh - 1) ? 1.f : 0.f;
        int mL = min(min(lr, S - 1 - lr), min(lc,     S - 1 - lc));
        int mR = min(min(lr, S - 1 - lr), min(lc + 1, S - 2 - lc));
        tm2L[k] = img ? mL : 0;
        tm2R[k] = img ? mR : 0;
        *(float2*)&su0p[l] = make_float2(u0l, u0r);
        *(float2*)&su1p[l] = make_float2(u1l, u1r);
    }
    __syncthreads();

    for (int t = 0; t < KF; ++t) {
        // ---- phase 1 (unconditional): w = 2x - x2
        #pragma unroll
        for (int k = 0; k < NKP; ++k) {
            const int l = l0 + 1280 * k;
            float2 ua = *(const float2*)&su0p[l - S];   // u0 above (b64)
            float  uw = su1p[l - 1];                    // u1 left-of-left (b32)
            float adjL = ua.x - u0L[k] + uw     - u1L[k];
            float adjR = ua.y - u0R[k] + u1L[k] - u1R[k];
            float xL = fmaf(TAU, yL[k] - adjL, x2L[k]);     // x*(1+TAU)
            float xR = fmaf(TAU, yR[k] - adjR, x2R[k]);
            wL[k] = fmaf(2.0f * INV_1PT, xL, -x2L[k]);      // 2x - x2
            wR[k] = fmaf(2.0f * INV_1PT, xR, -x2R[k]);
            *(float2*)&sw_raw[l] = make_float2(wL[k], wR[k]);
        }
        __syncthreads();
        // ---- phase 2: u, x2 update (selects keep inactive/OOB cells frozen)
        #pragma unroll
        for (int k = 0; k < NKP; ++k) {
            const int l = l0 + 1280 * k;
            float2 wb = *(const float2*)&sw_raw[l + S]; // w below (b64)
            float  wr = sw_raw[l + 2];                  // w right-of-right (b32)
            float dhL = ehf[k] * (wb.x - wL[k]);
            float dhR = ehf[k] * (wb.y - wR[k]);
            float dwL = ewL * (wR[k] - wL[k]);
            float dwR = ewR * (wr    - wR[k]);
            float v0L = fmaf(SIGMA, dhL, u0L[k]);
            float v1L = fmaf(SIGMA, dwL, u1L[k]);
            float v0R = fmaf(SIGMA, dhR, u0R[k]);
            float v1R = fmaf(SIGMA, dwR, u1R[k]);
            float ivL = fminf(THS * __builtin_amdgcn_rsqf(fmaf(v0L, v0L, v1L * v1L)), 1.f);
            float ivR = fminf(THS * __builtin_amdgcn_rsqf(fmaf(v0R, v0R, v1R * v1R)), 1.f);
            bool aL = t < tm2L[k], aR = t < tm2R[k];
            u0L[k] = aL ? fmaf(RHO, v0L * ivL - u0L[k], u0L[k]) : u0L[k];
            u1L[k] = aL ? fmaf(RHO, v1L * ivL - u1L[k], u1L[k]) : u1L[k];
            x2L[k] = aL ? fmaf(0.5f * RHO, wL[k] - x2L[k], x2L[k]) : x2L[k];
            u0R[k] = aR ? fmaf(RHO, v0R * ivR - u0R[k], u0R[k]) : u0R[k];
            u1R[k] = aR ? fmaf(RHO, v1R * ivR - u1R[k], u1R[k]) : u1R[k];
            x2R[k] = aR ? fmaf(0.5f * RHO, wR[k] - x2R[k], x2R[k]) : x2R[k];
            *(float2*)&su0p[l] = make_float2(u0L[k], u0R[k]);
            *(float2*)&su1p[l] = make_float2(u1L[k], u1R[k]);
        }
        __syncthreads();
    }

    // ---- store central 64x64 straight from registers
    if (cp >= 4 && cp < 36) {
        #pragma unroll
        for (int k = 0; k < NKP; ++k) {
            const int lr = rp + 16 * k;
            if (lr >= KF && lr < KF + TS) {
                size_t gi = plane + (size_t)(r0 + lr - KF) * Ww + gc;
                *(float2*)&x2_out[gi] = make_float2(x2L[k], x2R[k]);
                if (!last) u_out[gi >> 1] = make_float4(u0L[k], u1L[k], u0R[k], u1R[k]);
            }
        }
    }
}

extern "C" void kernel_launch(void* const* d_in, const int* in_sizes, int n_in,
                              void* d_out, int out_size, void* d_ws, size_t ws_size,
                              hipStream_t stream)
{
    const float* y = (const float*)d_in[0];
    float* out = (float*)d_out;
    const size_t NP = (size_t)Bb * Hh * Ww;   // 2M cells

    float*  ws  = (float*)d_ws;
    float*  x2A = ws;                          // 8 MB
    float*  x2B = ws + NP;                     // 8 MB
    float4* uA  = (float4*)(ws + 2 * NP);      // 16 MB
    float4* uB  = (float4*)(ws + 4 * NP);      // 16 MB
    // total ws use: 6*NP*4 = 48 MB; no memset needed (first=1 treats u as 0)

    dim3 grid(Ww / TS, Hh / TS, Bb);   // 8 x 8 x 8 = 512 blocks

    tv_fused<<<grid, NT, 0, stream>>>(y,   uB, y, x2A, uA, 1, 0);
    tv_fused<<<grid, NT, 0, stream>>>(x2A, uA, y, x2B, uB, 0, 0);
    tv_fused<<<grid, NT, 0, stream>>>(x2B, uB, y, x2A, uA, 0, 0);
    tv_fused<<<grid, NT, 0, stream>>>(x2A, uA, y, x2B, uB, 0, 0);
    tv_fused<<<grid, NT, 0, stream>>>(x2B, uB, y, out, uA, 0, 1);
}